// Round 13
// baseline (114.640 us; speedup 1.0000x reference)
//
#include <hip/hip_runtime.h>

// MHA: out = softmax_causal((XWq)(XWk)^T / 8) (XWv) Wo
// B=2 S=2048 DM=1024 H=16 d=64. Inputs fp32, output fp32, bf16 MFMA compute.

typedef __attribute__((ext_vector_type(8))) short v8s;   // 8 x bf16 (4 VGPRs)
typedef __attribute__((ext_vector_type(4))) short v4s;   // 4 x bf16 (2 VGPRs)
typedef __attribute__((ext_vector_type(4))) float v4f;   // MFMA accumulator

#define MFMA16(a, b, c) __builtin_amdgcn_mfma_f32_16x16x32_bf16(a, b, c, 0, 0, 0)

// K=16 bf16 MFMA: A-operand layout A[lr][k=lg*4+j] matches the QK^T C-layout
// directly (4 consecutive k per lane) -> P feeds PV with no repack.
#if defined(__has_builtin)
#if __has_builtin(__builtin_amdgcn_mfma_f32_16x16x16bf16_1k)
#define HAVE_MFMA_K16 1
#endif
#endif
__device__ __forceinline__ v4f mfma_k16(v4s a, v4s b, v4f c) {
#ifdef HAVE_MFMA_K16
  return __builtin_amdgcn_mfma_f32_16x16x16bf16_1k(a, b, c, 0, 0, 0);
#else
  asm volatile("v_mfma_f32_16x16x16_bf16 %0, %1, %2, %0"
               : "+v"(c)
               : "v"(a), "v"(b));
  return c;
#endif
}

#define GLOBAL_AS __attribute__((address_space(1)))
#define LDS_AS __attribute__((address_space(3)))

__device__ __forceinline__ void gload_lds16(const void* g, void* l) {
  // async global->LDS, 16B per lane; LDS dest = wave-uniform base + lane*16
  __builtin_amdgcn_global_load_lds((const GLOBAL_AS void*)g, (LDS_AS void*)l, 16, 0, 0);
}

__device__ __forceinline__ short f2bf(float f) {
  union { float f; unsigned u; } x; x.f = f;
  unsigned r = x.u + 0x7fffu + ((x.u >> 16) & 1u);  // RNE
  return (short)(r >> 16);
}

// pack 2 f32 -> 1 dword of 2 bf16 (RNE), lo16 = bf16(a), hi16 = bf16(b)
__device__ __forceinline__ unsigned cvtpk_bf16(float a, float b) {
  unsigned r;
  asm("v_cvt_pk_bf16_f32 %0, %1, %2" : "=v"(r) : "v"(a), "v"(b));
  return r;
}

// hardware 2^x (underflows to 0 for masked -1e30 scores)
__device__ __forceinline__ float exp2_hw(float x) {
  float r;
  asm("v_exp_f32 %0, %1" : "=v"(r) : "v"(x));
  return r;
}

// ---------------------------------------------------------------------------
// Weight transpose+cast: W[1024][1024] f32 ([k][n]) -> Wt[n][k] bf16, z=0..3.
// z0: w_q (scale 0.125*log2e folded -> QK scores land in exp2 domain),
// z1: w_k, z2: w_v, z3: w_o.  Wt layout: [Wto | Wtq | Wtk | Wtv] each 1M shorts.
// ---------------------------------------------------------------------------
__global__ __launch_bounds__(256) void wtrans_kernel(const float* __restrict__ w0,
                                                     const float* __restrict__ w1,
                                                     const float* __restrict__ w2,
                                                     const float* __restrict__ w3,
                                                     short* __restrict__ wtbase) {
  __shared__ __align__(16) short tile[64 * 72];
  const int NN = 1024;
  int z = blockIdx.z;
  const float* W = (z == 0) ? w0 : (z == 1) ? w1 : (z == 2) ? w2 : w3;
  short* Wt = wtbase + ((z < 3) ? ((size_t)(z + 1) << 20) : 0);
  float scale = (z == 0) ? 0.125f * 1.44269504f : 1.0f;
  int n0 = blockIdx.x * 64, k0 = blockIdx.y * 64;
  int t = threadIdx.x;
  int r = t >> 4;
  int c4 = (t & 15) * 4;
  for (int rr = r; rr < 64; rr += 16) {
    float4 f = *(const float4*)(W + (size_t)(k0 + rr) * NN + n0 + c4);
    tile[(c4 + 0) * 72 + rr] = f2bf(f.x * scale);
    tile[(c4 + 1) * 72 + rr] = f2bf(f.y * scale);
    tile[(c4 + 2) * 72 + rr] = f2bf(f.z * scale);
    tile[(c4 + 3) * 72 + rr] = f2bf(f.w * scale);
  }
  __syncthreads();
  int nr = t >> 2, kc = (t & 3) * 16;
  v8s v0 = *(const v8s*)&tile[nr * 72 + kc];
  v8s v1 = *(const v8s*)&tile[nr * 72 + kc + 8];
  *(v8s*)(Wt + (size_t)(n0 + nr) * NN + k0 + kc) = v0;
  *(v8s*)(Wt + (size_t)(n0 + nr) * NN + k0 + kc + 8) = v1;
}

// ---------------------------------------------------------------------------
// fp32 -> bf16 cast, 8 elems/thread, z selects src. grid (2048,1,3).
// ---------------------------------------------------------------------------
__global__ __launch_bounds__(256) void cast3_kernel(const float* __restrict__ s0,
                                                    const float* __restrict__ s1,
                                                    const float* __restrict__ s2,
                                                    short* __restrict__ dst,
                                                    size_t zstride) {
  int z = blockIdx.z;
  const float* src = (z == 0) ? s0 : (z == 1) ? s1 : s2;
  short* d = dst + (size_t)z * zstride;
  int i = (blockIdx.x * 256 + threadIdx.x) * 8;
  float4 f0 = *(const float4*)(src + i);
  float4 f1 = *(const float4*)(src + i + 4);
  v8s v;
  v[0] = f2bf(f0.x); v[1] = f2bf(f0.y); v[2] = f2bf(f0.z); v[3] = f2bf(f0.w);
  v[4] = f2bf(f1.x); v[5] = f2bf(f1.y); v[6] = f2bf(f1.z); v[7] = f2bf(f1.w);
  *(v8s*)(d + i) = v;
}

// ---------------------------------------------------------------------------
// GEMM (R8-proven): C = A[M][K] * Bt[N][K]^T, all-bf16, 128x128 tile, BK=32,
// 2-phase double-buffered, 32 KB LDS (5 blocks/CU), XOR-swizzled LDS via
// pre-swizzled DMA source (rule 21), XCD-aware remap (T1, nwg % 8 == 0).
// V_TRANS: bz==2 writes C transposed to Vt[bh][d][s] (fuses vtrans kernel).
// ---------------------------------------------------------------------------
template <bool OUT_F32, bool V_TRANS>
__global__ __launch_bounds__(256) void gemm2_kernel(
    const short* __restrict__ Ab, size_t sA,
    const short* __restrict__ Btb, size_t sB,
    short* __restrict__ Cb, float* __restrict__ Cf, size_t sC,
    short* __restrict__ Vt,
    int M, int N, int K) {
  __shared__ __align__(16) short As[2][128 * 32];  // 16 KB
  __shared__ __align__(16) short Bs[2][128 * 32];  // 16 KB

  // XCD-contiguous remap (bijective since nwg % 8 == 0)
  int gx = gridDim.x, gy = gridDim.y;
  int id = blockIdx.x + gx * (blockIdx.y + gy * blockIdx.z);
  int nwg = gx * gy * gridDim.z;
  int v = (id & 7) * (nwg >> 3) + (id >> 3);
  int bx = v % gx;
  int by = (v / gx) % gy;
  int bz = v / (gx * gy);

  const short* A = Ab + (size_t)bz * sA;
  const short* Bt = Btb + (size_t)bz * sB;
  int row0 = by * 128, col0 = bx * 128;
  int t = threadIdx.x, lane = t & 63, w = t >> 6;
  int wm = (w >> 1) * 64, wn = (w & 1) * 64;
  int lr = lane & 15, lg = lane >> 4;

  v4f acc[4][4];
#pragma unroll
  for (int i = 0; i < 4; ++i)
#pragma unroll
    for (int j = 0; j < 4; ++j) acc[i][j] = {0.f, 0.f, 0.f, 0.f};

  // DMA staging: 1KB chunks of 16 rows x 32k; wave w stages chunks {w, w+4}.
  // lane l -> phys row l>>2, slot l&3; source col slot = (l&3) ^ s(row),
  // s(row) = (row ^ (row>>2)) & 3 == read-side rsw.
  int rl = lane >> 2, sl = lane & 3;
  int scol = ((sl ^ (rl ^ (rl >> 2))) & 3) * 8;
  const short* gA = A + (size_t)(row0 + w * 16 + rl) * K + scol;
  const short* gB = Bt + (size_t)(col0 + w * 16 + rl) * K + scol;
  const size_t rstep = (size_t)64 * K;

#define GEMM_STAGE(buf, k0_)                              \
  do {                                                    \
    gload_lds16(gA + (k0_), &As[buf][w * 512]);           \
    gload_lds16(gA + rstep + (k0_), &As[buf][(w + 4) * 512]); \
    gload_lds16(gB + (k0_), &Bs[buf][w * 512]);           \
    gload_lds16(gB + rstep + (k0_), &Bs[buf][(w + 4) * 512]); \
  } while (0)

  GEMM_STAGE(0, 0);
  __syncthreads();
  int cur = 0;
  int rsw = (lr ^ (lr >> 2)) & 3;
  for (int k0 = 0; k0 < K; k0 += 32) {
    if (k0 + 32 < K) GEMM_STAGE(cur ^ 1, k0 + 32);
    v8s af[4], bg[4];
#pragma unroll
    for (int mf = 0; mf < 4; ++mf)
      af[mf] = *(const v8s*)&As[cur][(wm + mf * 16 + lr) * 32 + ((lg ^ rsw) * 8)];
#pragma unroll
    for (int nf = 0; nf < 4; ++nf)
      bg[nf] = *(const v8s*)&Bs[cur][(wn + nf * 16 + lr) * 32 + ((lg ^ rsw) * 8)];
    __builtin_amdgcn_s_setprio(1);
#pragma unroll
    for (int mf = 0; mf < 4; ++mf)
#pragma unroll
      for (int nf = 0; nf < 4; ++nf)
        acc[mf][nf] = MFMA16(af[mf], bg[nf], acc[mf][nf]);
    __builtin_amdgcn_s_setprio(0);
    __syncthreads();  // drains prefetch vmcnt + all LDS reads; 1 barrier/iter
    cur ^= 1;
  }
#undef GEMM_STAGE

  if (V_TRANS && bz == 2) {
    // write V transposed: Vt[bh][d][s], bh=b*16+h, h=col>>6, d=col&63;
    // the 4 acc rows are consecutive s -> one uint2 (4 bf16) store.
#pragma unroll
    for (int mf = 0; mf < 4; ++mf)
#pragma unroll
      for (int nf = 0; nf < 4; ++nf) {
        int col = col0 + wn + nf * 16 + lr;
        int row = row0 + wm + mf * 16 + lg * 4;
        int bh = ((row >> 11) << 4) + (col >> 6);
        int d = col & 63, s = row & 2047;
        uint2 u;
        u.x = cvtpk_bf16(acc[mf][nf][0], acc[mf][nf][1]);
        u.y = cvtpk_bf16(acc[mf][nf][2], acc[mf][nf][3]);
        *(uint2*)&Vt[((size_t)bh * 64 + d) * 2048 + s] = u;
      }
  } else {
#pragma unroll
    for (int mf = 0; mf < 4; ++mf)
#pragma unroll
      for (int nf = 0; nf < 4; ++nf)
#pragma unroll
        for (int r = 0; r < 4; ++r) {
          int row = row0 + wm + mf * 16 + lg * 4 + r;
          int col = col0 + wn + nf * 16 + lr;
          if (OUT_F32)
            (Cf + (size_t)bz * sC)[(size_t)row * N + col] = acc[mf][nf][r];
          else
            (Cb + (size_t)bz * sC)[(size_t)row * N + col] = f2bf(acc[mf][nf][r]);
        }
  }
}

// ---------------------------------------------------------------------------
// Causal flash attention, 512 threads / 8 waves per block.
// Wave w: q-row group g=w&3 (16 rows), key-half hh=w>>2 (32 of 64 keys/tile).
// Max-free exp2 softmax, key-partitioned partial O/den per wave, one
// cross-wave reduction at the end (LDS scratch reuses K/V bufs).
// PV uses 16x16x16 MFMAs: the QK^T C-layout (k=t2*16+lg*4+r per lane) IS the
// K=16 A-operand layout, so P goes cvt_pk -> MFMA with NO LDS round-trip.
// Grid (16,32)=512 blocks; v=(id&7)*64+(id>>3) -> XCD x owns bh [4x,4x+4)
// (K/V L2-resident); px=v&15 -> q-tiles {31-px, px} sequential (33 iters).
// ---------------------------------------------------------------------------
__global__ __launch_bounds__(512, 4) void attn_kernel(const short* __restrict__ Qm,
                                                      const short* __restrict__ Km,
                                                      const short* __restrict__ Vt_g,
                                                      short* __restrict__ Cm) {
  const int S = 2048, DM = 1024;
  // Ks[2][4096] | Vs[2][4096]  (32 KB); scr (cross-wave reduce) reuses it
  __shared__ __align__(16) short lds[16384];
  short* Ks0 = lds;
  short* Vs0 = lds + 8192;
  v4f* scr = (v4f*)lds;

  int id = blockIdx.y * 16 + blockIdx.x;
  int v = (id & 7) * 64 + (id >> 3);    // XCD-contiguous remap (bijective)
  int bh = v >> 4;
  int px = v & 15;                      // q-tile pair {31-px, px}
  int b = bh >> 4, h = bh & 15;
  int t = threadIdx.x, lane = t & 63, w = t >> 6;  // w 0..7
  int g = w & 3, hh = w >> 2;
  int lr = lane & 15, lg = lane >> 4;
  size_t base = (size_t)b * S * DM + h * 64;
  size_t vbase = (size_t)bh * 64 * S;

  // staging: 16 chunks of 1KB (8 rows x 128B); wave w stages K-chunk w + V-chunk w
  int srow = w * 8 + (lane >> 3);
  int scol = ((lane & 7) ^ (lane >> 3)) * 8;
  const short* gK = Km + base + (size_t)srow * DM + scol;
  const short* gV = Vt_g + vbase + (size_t)srow * S + scol;
  int sw = (lr & 7) * 8;  // read swizzle (slot XOR; operands are 8-short-aligned)

  const v4s vone4 = {0x3F80, 0x3F80, 0x3F80, 0x3F80};  // bf16 1.0 x4

#define ATTN_STAGE(buf, kt_)                                                  \
  do {                                                                        \
    size_t k0_ = (size_t)(kt_) * 64;                                          \
    gload_lds16(gK + k0_ * DM, &Ks0[(buf) * 4096 + w * 512]);                 \
    gload_lds16(gV + k0_, &Vs0[(buf) * 4096 + w * 512]);                      \
  } while (0)

  short* Cp = Cm + base;

  // V-fragment column offsets (hoisted): t2=0/1, k = hh*32 + t2*16 + lg*4
  int vc0 = ((hh * 32 + 0 + (lg >> 1) * 8) ^ sw) + (lg & 1) * 4;
  int vc1 = ((hh * 32 + 16 + (lg >> 1) * 8) ^ sw) + (lg & 1) * 4;

#pragma unroll 1
  for (int qsel = 0; qsel < 2; ++qsel) {
    int qt = qsel ? px : (31 - px);  // long q-tile first
    int qbase = qt * 64 + g * 16;
    int qg = qbase + lr;
    int nkt = qt + 1;

    // Q fragments (B-operand rows, indexed by lr); 0.125*log2e folded into Wq
    const short* Qp = Qm + base + (size_t)(qbase + lr) * DM + lg * 8;
    v8s q0 = *(const v8s*)Qp;
    v8s q1 = *(const v8s*)(Qp + 32);

    v4f o[5];  // [0..3] = O cols d4*16+lr; [4] = sum(P) via ones-MFMA
#pragma unroll
    for (int d4 = 0; d4 < 5; ++d4) o[d4] = {0.f, 0.f, 0.f, 0.f};

    ATTN_STAGE(0, 0);
    __syncthreads();
    int cur = 0;
#pragma unroll 1
    for (int kt = 0; kt < nkt; ++kt) {
      if (kt + 1 < nkt) ATTN_STAGE(cur ^ 1, kt + 1);
      int k0 = kt * 64;
      const short* Kc = &Ks0[cur * 4096];
      const short* Vc = &Vs0[cur * 4096];

      // operand loads: K (b128, x32 A-frags) + V (b64, x16 B-frags)
      v8s ka0[2], ka1[2];
#pragma unroll
      for (int t2 = 0; t2 < 2; ++t2) {
        int kr = hh * 32 + t2 * 16 + lr;
        ka0[t2] = *(const v8s*)&Kc[kr * 64 + ((lg * 8) ^ sw)];
        ka1[t2] = *(const v8s*)&Kc[kr * 64 + ((32 + lg * 8) ^ sw)];
      }
      v4s vf0[4], vf1[4];
#pragma unroll
      for (int d4 = 0; d4 < 4; ++d4) {
        int row = (d4 * 16 + lr) * 64;
        vf0[d4] = *(const v4s*)&Vc[row + vc0];
        vf1[d4] = *(const v4s*)&Vc[row + vc1];
      }

      // S^T: st[t2][r] = S[q=lr][k0 + hh*32 + t2*16 + lg*4 + r] (exp2 domain)
      v4f st[2];
      __builtin_amdgcn_s_setprio(1);
#pragma unroll
      for (int t2 = 0; t2 < 2; ++t2) {
        v4f s = {0.f, 0.f, 0.f, 0.f};
        s = MFMA16(ka0[t2], q0, s);
        s = MFMA16(ka1[t2], q1, s);
        st[t2] = s;
      }
      __builtin_amdgcn_s_setprio(0);

      if (kt == nkt - 1) {  // causal mask (only last tile can violate)
#pragma unroll
        for (int t2 = 0; t2 < 2; ++t2)
#pragma unroll
          for (int r = 0; r < 4; ++r)
            if (k0 + hh * 32 + t2 * 16 + lg * 4 + r > qg) st[t2][r] = -1e30f;
      }

      // P = exp2(st), packed straight into K=16 A-fragments (no LDS bounce)
      uint2 paw0, paw1;
      paw0.x = cvtpk_bf16(exp2_hw(st[0][0]), exp2_hw(st[0][1]));
      paw0.y = cvtpk_bf16(exp2_hw(st[0][2]), exp2_hw(st[0][3]));
      paw1.x = cvtpk_bf16(exp2_hw(st[1][0]), exp2_hw(st[1][1]));
      paw1.y = cvtpk_bf16(exp2_hw(st[1][2]), exp2_hw(st[1][3]));
      v4s pa0 = *(v4s*)&paw0;
      v4s pa1 = *(v4s*)&paw1;

      // PV (two K=16 sub-tiles) + ones-MFMA denominator
      __builtin_amdgcn_s_setprio(1);
#pragma unroll
      for (int d4 = 0; d4 < 4; ++d4) {
        o[d4] = mfma_k16(pa0, vf0[d4], o[d4]);
        o[d4] = mfma_k16(pa1, vf1[d4], o[d4]);
      }
      o[4] = mfma_k16(pa0, vone4, o[4]);
      o[4] = mfma_k16(pa1, vone4, o[4]);
      __builtin_amdgcn_s_setprio(0);
      __syncthreads();  // drains prefetch vmcnt + LDS reads; 1 barrier/iter
      cur ^= 1;
    }

    // cross-wave reduce (hh=1 partials into hh=0) and store
    if (hh == 1) {
#pragma unroll
      for (int d4 = 0; d4 < 5; ++d4) scr[(g * 5 + d4) * 64 + lane] = o[d4];
    }
    __syncthreads();
    if (hh == 0) {
#pragma unroll
      for (int d4 = 0; d4 < 5; ++d4) {
        v4f p = scr[(g * 5 + d4) * 64 + lane];
#pragma unroll
        for (int r = 0; r < 4; ++r) o[d4][r] += p[r];
      }
      float sv[4];
#pragma unroll
      for (int r = 0; r < 4; ++r) sv[r] = 1.0f / o[4][r];
#pragma unroll
      for (int r = 0; r < 4; ++r)
#pragma unroll
        for (int d4 = 0; d4 < 4; ++d4)
          Cp[(size_t)(qbase + lg * 4 + r) * DM + d4 * 16 + lr] =
              f2bf(o[d4][r] * sv[r]);
    }
    __syncthreads();  // scr/K/V region free before next q-tile stages into it
  }
#undef ATTN_STAGE
}

// ---------------------------------------------------------------------------
extern "C" void kernel_launch(void* const* d_in, const int* in_sizes, int n_in,
                              void* d_out, int out_size, void* d_ws, size_t ws_size,
                              hipStream_t stream) {
  const float* q_in = (const float*)d_in[0];
  const float* k_in = (const float*)d_in[1];
  const float* v_in = (const float*)d_in[2];
  // d_in[3] = mask: causal triu(k=1), applied analytically in attn_kernel
  const float* w_q = (const float*)d_in[4];
  const float* w_k = (const float*)d_in[5];
  const float* w_v = (const float*)d_in[6];
  const float* w_o = (const float*)d_in[7];
  float* outp = (float*)d_out;

  short* ws = (short*)d_ws;
  const size_t M1 = (size_t)1 << 20;  // 1M shorts = 2MB
  // Layout (64MB of ws): Wt[0:4M)=[Wto|Wtq|Wtk|Wtv], X[4:16M) bf16
  // QKV inputs, Qb[16:20M), Kb[20:24M), Vtg[24:28M), Cb[28:32M).
  short* Wto = ws;
  short* Wtq = ws + 1 * M1;
  short* X = ws + 4 * M1;
  short* Qb = ws + 16 * M1;
  short* Vtg = ws + 24 * M1;
  short* Cb = ws + 28 * M1;
  dim3 tb(256);
  dim3 tba(512);

  wtrans_kernel<<<dim3(16, 16, 4), tb, 0, stream>>>(w_q, w_k, w_v, w_o, ws);
  cast3_kernel<<<dim3(2048, 1, 3), tb, 0, stream>>>(q_in, k_in, v_in, X, 4 * M1);
  // QKV projections: bf16 DMA-staged (R8-proven); bz=2 writes Vtg transposed
  gemm2_kernel<false, true><<<dim3(8, 32, 3), tb, 0, stream>>>(
      X, 4 * M1, Wtq, M1, Qb, nullptr, 4 * M1, Vtg, 4096, 1024, 1024);
  attn_kernel<<<dim3(16, 32), tba, 0, stream>>>(Qb, Qb + 4 * M1, Vtg, Cb);
  gemm2_kernel<true, false><<<dim3(8, 32, 1), tb, 0, stream>>>(
      Cb, 0, Wto, 0, nullptr, outp, 0, nullptr, 4096, 1024, 1024);
}

// Round 14
// 113.596 us; speedup vs baseline: 1.0092x; 1.0092x over previous
//
#include <hip/hip_runtime.h>

// MHA: out = softmax_causal((XWq)(XWk)^T / 8) (XWv) Wo
// B=2 S=2048 DM=1024 H=16 d=64. Inputs fp32, output fp32, bf16 MFMA compute.

typedef __attribute__((ext_vector_type(8))) short v8s;   // 8 x bf16 (4 VGPRs)
typedef __attribute__((ext_vector_type(4))) float v4f;   // MFMA accumulator

#define MFMA16(a, b, c) __builtin_amdgcn_mfma_f32_16x16x32_bf16(a, b, c, 0, 0, 0)

#define GLOBAL_AS __attribute__((address_space(1)))
#define LDS_AS __attribute__((address_space(3)))

__device__ __forceinline__ void gload_lds16(const void* g, void* l) {
  // async global->LDS, 16B per lane; LDS dest = wave-uniform base + lane*16
  __builtin_amdgcn_global_load_lds((const GLOBAL_AS void*)g, (LDS_AS void*)l, 16, 0, 0);
}

__device__ __forceinline__ short f2bf(float f) {
  union { float f; unsigned u; } x; x.f = f;
  unsigned r = x.u + 0x7fffu + ((x.u >> 16) & 1u);  // RNE
  return (short)(r >> 16);
}

// pack 2 f32 -> 1 dword of 2 bf16 (RNE), lo16 = bf16(a), hi16 = bf16(b)
__device__ __forceinline__ unsigned cvtpk_bf16(float a, float b) {
  unsigned r;
  asm("v_cvt_pk_bf16_f32 %0, %1, %2" : "=v"(r) : "v"(a), "v"(b));
  return r;
}

// hardware 2^x (underflows to 0 for masked -1e30 scores)
__device__ __forceinline__ float exp2_hw(float x) {
  float r;
  asm("v_exp_f32 %0, %1" : "=v"(r) : "v"(x));
  return r;
}

// ---------------------------------------------------------------------------
// Fused prep: weight transpose+cast (4 slices) + QKV input f32->bf16 cast
// (3 slabs), one launch. Blocks [0,1024): wtrans (z=bid>>8; z0 Wq with
// 0.125*log2e folded, z1 Wk, z2 Wv, z3 Wo -> Wt[n][k] bf16 at
// [Wto|Wtq|Wtk|Wtv]). Blocks [1024,7168): cast q/k/v -> X (bf16), 2048
// blocks per slab, 8 elems/thread.
// ---------------------------------------------------------------------------
__global__ __launch_bounds__(256) void prep_kernel(const float* __restrict__ w0,
                                                   const float* __restrict__ w1,
                                                   const float* __restrict__ w2,
                                                   const float* __restrict__ w3,
                                                   short* __restrict__ wtbase,
                                                   const float* __restrict__ s0,
                                                   const float* __restrict__ s1,
                                                   const float* __restrict__ s2,
                                                   short* __restrict__ X,
                                                   size_t xstride) {
  __shared__ __align__(16) short tile[64 * 72];
  const int NN = 1024;
  int bid = blockIdx.x;
  int t = threadIdx.x;
  if (bid < 1024) {
    int z = bid >> 8;
    int rem = bid & 255;
    int n0 = (rem & 15) * 64, k0 = (rem >> 4) * 64;
    const float* W = (z == 0) ? w0 : (z == 1) ? w1 : (z == 2) ? w2 : w3;
    short* Wt = wtbase + ((z < 3) ? ((size_t)(z + 1) << 20) : 0);
    float scale = (z == 0) ? 0.125f * 1.44269504f : 1.0f;
    int r = t >> 4;
    int c4 = (t & 15) * 4;
    for (int rr = r; rr < 64; rr += 16) {
      float4 f = *(const float4*)(W + (size_t)(k0 + rr) * NN + n0 + c4);
      tile[(c4 + 0) * 72 + rr] = f2bf(f.x * scale);
      tile[(c4 + 1) * 72 + rr] = f2bf(f.y * scale);
      tile[(c4 + 2) * 72 + rr] = f2bf(f.z * scale);
      tile[(c4 + 3) * 72 + rr] = f2bf(f.w * scale);
    }
    __syncthreads();
    int nr = t >> 2, kc = (t & 3) * 16;
    v8s v0 = *(const v8s*)&tile[nr * 72 + kc];
    v8s v1 = *(const v8s*)&tile[nr * 72 + kc + 8];
    *(v8s*)(Wt + (size_t)(n0 + nr) * NN + k0 + kc) = v0;
    *(v8s*)(Wt + (size_t)(n0 + nr) * NN + k0 + kc + 8) = v1;
  } else {
    int c = bid - 1024;
    int z = c >> 11;
    const float* src = (z == 0) ? s0 : (z == 1) ? s1 : s2;
    short* d = X + (size_t)z * xstride;
    int i = ((c & 2047) * 256 + t) * 8;
    float4 f0 = *(const float4*)(src + i);
    float4 f1 = *(const float4*)(src + i + 4);
    v8s v;
    v[0] = f2bf(f0.x); v[1] = f2bf(f0.y); v[2] = f2bf(f0.z); v[3] = f2bf(f0.w);
    v[4] = f2bf(f1.x); v[5] = f2bf(f1.y); v[6] = f2bf(f1.z); v[7] = f2bf(f1.w);
    *(v8s*)(d + i) = v;
  }
}

// ---------------------------------------------------------------------------
// GEMM, 64x128 tile (TLP-boosted): C = A[M][K] * Bt[N][K]^T, all-bf16,
// BK=32, 2-phase double-buffered, 24 KB LDS -> 6 blocks/CU (24 waves/CU),
// XOR-swizzled LDS via pre-swizzled DMA source (rule 21), XCD remap (T1).
// 4 waves: wave w computes all 64 rows x cols [w*32, w*32+32) (acc 4x2).
// A-chunk w staged by wave w (4 chunks); B chunks {w, w+4} (8 chunks).
// V_TRANS: bz==2 writes C transposed to Vt[bh][d][s] (fused vtrans).
// ---------------------------------------------------------------------------
template <bool OUT_F32, bool V_TRANS>
__global__ __launch_bounds__(256, 6) void gemm64_kernel(
    const short* __restrict__ Ab, size_t sA,
    const short* __restrict__ Btb, size_t sB,
    short* __restrict__ Cb, float* __restrict__ Cf, size_t sC,
    short* __restrict__ Vt,
    int M, int N, int K) {
  __shared__ __align__(16) short As[2][64 * 32];   // 8 KB
  __shared__ __align__(16) short Bs[2][128 * 32];  // 16 KB

  // XCD-contiguous remap (bijective since nwg % 8 == 0)
  int gx = gridDim.x, gy = gridDim.y;
  int id = blockIdx.x + gx * (blockIdx.y + gy * blockIdx.z);
  int nwg = gx * gy * gridDim.z;
  int v = (id & 7) * (nwg >> 3) + (id >> 3);
  int bx = v % gx;
  int by = (v / gx) % gy;
  int bz = v / (gx * gy);

  const short* A = Ab + (size_t)bz * sA;
  const short* Bt = Btb + (size_t)bz * sB;
  int row0 = by * 64, col0 = bx * 128;
  int t = threadIdx.x, lane = t & 63, w = t >> 6;
  int wn = w * 32;
  int lr = lane & 15, lg = lane >> 4;

  v4f acc[4][2];
#pragma unroll
  for (int i = 0; i < 4; ++i)
#pragma unroll
    for (int j = 0; j < 2; ++j) acc[i][j] = {0.f, 0.f, 0.f, 0.f};

  // DMA staging: 1KB chunks of 16 rows x 32k. lane l -> phys row l>>2,
  // slot l&3; source col slot = (l&3) ^ s(row), s(row)=(row^(row>>2))&3.
  int rl = lane >> 2, sl = lane & 3;
  int scol = ((sl ^ (rl ^ (rl >> 2))) & 3) * 8;
  const short* gA = A + (size_t)(row0 + w * 16 + rl) * K + scol;
  const short* gB = Bt + (size_t)(col0 + w * 16 + rl) * K + scol;
  const size_t rstep = (size_t)64 * K;

#define GEMM_STAGE(buf, k0_)                                  \
  do {                                                        \
    gload_lds16(gA + (k0_), &As[buf][w * 512]);               \
    gload_lds16(gB + (k0_), &Bs[buf][w * 512]);               \
    gload_lds16(gB + rstep + (k0_), &Bs[buf][(w + 4) * 512]); \
  } while (0)

  GEMM_STAGE(0, 0);
  __syncthreads();
  int cur = 0;
  int rsw = (lr ^ (lr >> 2)) & 3;
  for (int k0 = 0; k0 < K; k0 += 32) {
    if (k0 + 32 < K) GEMM_STAGE(cur ^ 1, k0 + 32);
    v8s af[4], bg[2];
#pragma unroll
    for (int mf = 0; mf < 4; ++mf)
      af[mf] = *(const v8s*)&As[cur][(mf * 16 + lr) * 32 + ((lg ^ rsw) * 8)];
#pragma unroll
    for (int nf = 0; nf < 2; ++nf)
      bg[nf] = *(const v8s*)&Bs[cur][(wn + nf * 16 + lr) * 32 + ((lg ^ rsw) * 8)];
    __builtin_amdgcn_s_setprio(1);
#pragma unroll
    for (int mf = 0; mf < 4; ++mf)
#pragma unroll
      for (int nf = 0; nf < 2; ++nf)
        acc[mf][nf] = MFMA16(af[mf], bg[nf], acc[mf][nf]);
    __builtin_amdgcn_s_setprio(0);
    __syncthreads();  // drains prefetch vmcnt + all LDS reads; 1 barrier/iter
    cur ^= 1;
  }
#undef GEMM_STAGE

  if (V_TRANS && bz == 2) {
    // write V transposed: Vt[bh][d][s], bh=b*16+h, h=col>>6, d=col&63;
    // the 4 acc rows are consecutive s -> one uint2 (4 bf16) store.
#pragma unroll
    for (int mf = 0; mf < 4; ++mf)
#pragma unroll
      for (int nf = 0; nf < 2; ++nf) {
        int col = col0 + wn + nf * 16 + lr;
        int row = row0 + mf * 16 + lg * 4;
        int bh = ((row >> 11) << 4) + (col >> 6);
        int d = col & 63, s = row & 2047;
        uint2 u;
        u.x = cvtpk_bf16(acc[mf][nf][0], acc[mf][nf][1]);
        u.y = cvtpk_bf16(acc[mf][nf][2], acc[mf][nf][3]);
        *(uint2*)&Vt[((size_t)bh * 64 + d) * 2048 + s] = u;
      }
  } else {
#pragma unroll
    for (int mf = 0; mf < 4; ++mf)
#pragma unroll
      for (int nf = 0; nf < 2; ++nf)
#pragma unroll
        for (int r = 0; r < 4; ++r) {
          int row = row0 + mf * 16 + lg * 4 + r;
          int col = col0 + wn + nf * 16 + lr;
          if (OUT_F32)
            (Cf + (size_t)bz * sC)[(size_t)row * N + col] = acc[mf][nf][r];
          else
            (Cb + (size_t)bz * sC)[(size_t)row * N + col] = f2bf(acc[mf][nf][r]);
        }
  }
}

// ---------------------------------------------------------------------------
// Causal flash attention (R12-proven), 512 threads / 8 waves per block.
// Wave w: q-row group g=w&3 (16 rows), key-half hh=w>>2 (32 of 64 keys/tile).
// Max-free exp2 softmax is associative -> key-partitioned partial O/den per
// wave, one cross-wave reduction at the end (LDS scratch reuses K/V bufs).
// Grid (16,32)=512 blocks; v=(id&7)*64+(id>>3) -> XCD x owns bh [4x,4x+4)
// (K/V L2-resident); px=v&15 -> q-tiles {31-px, px} sequential (33 iters).
// ---------------------------------------------------------------------------
__global__ __launch_bounds__(512, 4) void attn_kernel(const short* __restrict__ Qm,
                                                      const short* __restrict__ Km,
                                                      const short* __restrict__ Vt_g,
                                                      short* __restrict__ Cm) {
  const int S = 2048, DM = 1024;
  // Ks[2][4096] | Vs[2][4096] | Pt[8][640]  (43 KB); scr reuses Ks/Vs (20 KB)
  __shared__ __align__(16) short lds[21504];
  short* Ks0 = lds;
  short* Vs0 = lds + 8192;
  short* Pt = lds + 16384;
  v4f* scr = (v4f*)lds;

  int id = blockIdx.y * 16 + blockIdx.x;
  int v = (id & 7) * 64 + (id >> 3);    // XCD-contiguous remap (bijective)
  int bh = v >> 4;
  int px = v & 15;                      // q-tile pair {31-px, px}
  int b = bh >> 4, h = bh & 15;
  int t = threadIdx.x, lane = t & 63, w = t >> 6;  // w 0..7
  int g = w & 3, hh = w >> 2;
  int lr = lane & 15, lg = lane >> 4;
  size_t base = (size_t)b * S * DM + h * 64;
  size_t vbase = (size_t)bh * 64 * S;

  // staging: 16 chunks of 1KB (8 rows x 128B); wave w stages K-chunk w + V-chunk w
  int srow = w * 8 + (lane >> 3);
  int scol = ((lane & 7) ^ (lane >> 3)) * 8;
  const short* gK = Km + base + (size_t)srow * DM + scol;
  const short* gV = Vt_g + vbase + (size_t)srow * S + scol;
  int sw = (lr & 7) * 8;  // read swizzle (row & 7 == lr & 7 everywhere we read)

  const v8s vone = {0x3F80, 0x3F80, 0x3F80, 0x3F80,
                    0x3F80, 0x3F80, 0x3F80, 0x3F80};  // bf16 1.0 x8

#define ATTN_STAGE(buf, kt_)                                                  \
  do {                                                                        \
    size_t k0_ = (size_t)(kt_) * 64;                                          \
    gload_lds16(gK + k0_ * DM, &Ks0[(buf) * 4096 + w * 512]);                 \
    gload_lds16(gV + k0_, &Vs0[(buf) * 4096 + w * 512]);                      \
  } while (0)

  short* Cp = Cm + base;

#pragma unroll 1
  for (int qsel = 0; qsel < 2; ++qsel) {
    int qt = qsel ? px : (31 - px);  // long q-tile first
    int qbase = qt * 64 + g * 16;
    int qg = qbase + lr;
    int nkt = qt + 1;

    // Q fragments (B-operand rows, indexed by lr); 0.125*log2e folded into Wq
    const short* Qp = Qm + base + (size_t)(qbase + lr) * DM + lg * 8;
    v8s q0 = *(const v8s*)Qp;
    v8s q1 = *(const v8s*)(Qp + 32);

    v4f o[5];  // [0..3] = O cols d4*16+lr; [4] = sum(P) via ones-MFMA
#pragma unroll
    for (int d4 = 0; d4 < 5; ++d4) o[d4] = {0.f, 0.f, 0.f, 0.f};

    ATTN_STAGE(0, 0);
    __syncthreads();
    int cur = 0;
#pragma unroll 1
    for (int kt = 0; kt < nkt; ++kt) {
      if (kt + 1 < nkt) ATTN_STAGE(cur ^ 1, kt + 1);
      int k0 = kt * 64;
      const short* Kc = &Ks0[cur * 4096];
      const short* Vc = &Vs0[cur * 4096];

      // operand loads: this wave's key-half hh
      v8s ka0[2], ka1[2], vf[4];
#pragma unroll
      for (int t2 = 0; t2 < 2; ++t2) {
        int kr = hh * 32 + t2 * 16 + lr;
        ka0[t2] = *(const v8s*)&Kc[kr * 64 + ((lg * 8) ^ sw)];
        ka1[t2] = *(const v8s*)&Kc[kr * 64 + ((32 + lg * 8) ^ sw)];
      }
#pragma unroll
      for (int d4 = 0; d4 < 4; ++d4)
        vf[d4] = *(const v8s*)&Vc[(d4 * 16 + lr) * 64 + ((hh * 32 + lg * 8) ^ sw)];

      // S^T: st[t2][r] = S[q=lr][k0 + hh*32 + t2*16 + lg*4 + r] (exp2 domain)
      v4f st[2];
      __builtin_amdgcn_s_setprio(1);
#pragma unroll
      for (int t2 = 0; t2 < 2; ++t2) {
        v4f s = {0.f, 0.f, 0.f, 0.f};
        s = MFMA16(ka0[t2], q0, s);
        s = MFMA16(ka1[t2], q1, s);
        st[t2] = s;
      }
      __builtin_amdgcn_s_setprio(0);

      if (kt == nkt - 1) {  // causal mask (only last tile can violate)
#pragma unroll
        for (int t2 = 0; t2 < 2; ++t2)
#pragma unroll
          for (int r = 0; r < 4; ++r)
            if (k0 + hh * 32 + t2 * 16 + lg * 4 + r > qg) st[t2][r] = -1e30f;
      }

      // P = exp2(st); pack bf16; store to wave-private LDS
#pragma unroll
      for (int t2 = 0; t2 < 2; ++t2) {
        uint2 u;
        u.x = cvtpk_bf16(exp2_hw(st[t2][0]), exp2_hw(st[t2][1]));
        u.y = cvtpk_bf16(exp2_hw(st[t2][2]), exp2_hw(st[t2][3]));
        *(uint2*)&Pt[w * 640 + lr * 40 + t2 * 16 + lg * 4] = u;
      }
      v8s pa = *(const v8s*)&Pt[w * 640 + lr * 40 + lg * 8];

      // PV over this key-half + ones-MFMA denominator
      __builtin_amdgcn_s_setprio(1);
#pragma unroll
      for (int d4 = 0; d4 < 4; ++d4) o[d4] = MFMA16(pa, vf[d4], o[d4]);
      o[4] = MFMA16(pa, vone, o[4]);
      __builtin_amdgcn_s_setprio(0);
      __syncthreads();  // drains prefetch vmcnt + LDS reads; 1 barrier/iter
      cur ^= 1;
    }

    // cross-wave reduce (hh=1 partials into hh=0) and store
    if (hh == 1) {
#pragma unroll
      for (int d4 = 0; d4 < 5; ++d4) scr[(g * 5 + d4) * 64 + lane] = o[d4];
    }
    __syncthreads();
    if (hh == 0) {
#pragma unroll
      for (int d4 = 0; d4 < 5; ++d4) {
        v4f p = scr[(g * 5 + d4) * 64 + lane];
#pragma unroll
        for (int r = 0; r < 4; ++r) o[d4][r] += p[r];
      }
      float sv[4];
#pragma unroll
      for (int r = 0; r < 4; ++r) sv[r] = 1.0f / o[4][r];
#pragma unroll
      for (int r = 0; r < 4; ++r)
#pragma unroll
        for (int d4 = 0; d4 < 4; ++d4)
          Cp[(size_t)(qbase + lg * 4 + r) * DM + d4 * 16 + lr] =
              f2bf(o[d4][r] * sv[r]);
    }
    __syncthreads();  // scr/K/V region free before next q-tile stages into it
  }
#undef ATTN_STAGE
}

// ---------------------------------------------------------------------------
extern "C" void kernel_launch(void* const* d_in, const int* in_sizes, int n_in,
                              void* d_out, int out_size, void* d_ws, size_t ws_size,
                              hipStream_t stream) {
  const float* q_in = (const float*)d_in[0];
  const float* k_in = (const float*)d_in[1];
  const float* v_in = (const float*)d_in[2];
  // d_in[3] = mask: causal triu(k=1), applied analytically in attn_kernel
  const float* w_q = (const float*)d_in[4];
  const float* w_k = (const float*)d_in[5];
  const float* w_v = (const float*)d_in[6];
  const float* w_o = (const float*)d_in[7];
  float* outp = (float*)d_out;

  short* ws = (short*)d_ws;
  const size_t M1 = (size_t)1 << 20;  // 1M shorts = 2MB
  // Layout (64MB of ws): Wt[0:4M)=[Wto|Wtq|Wtk|Wtv], X[4:16M) bf16
  // QKV inputs, Qb[16:20M), Kb[20:24M), Vtg[24:28M), Cb[28:32M).
  short* Wto = ws;
  short* Wtq = ws + 1 * M1;
  short* X = ws + 4 * M1;
  short* Qb = ws + 16 * M1;
  short* Vtg = ws + 24 * M1;
  short* Cb = ws + 28 * M1;
  dim3 tb(256);
  dim3 tba(512);

  // fused weight-transpose + input-cast (one launch)
  prep_kernel<<<dim3(7168), tb, 0, stream>>>(w_q, w_k, w_v, w_o, ws,
                                             q_in, k_in, v_in, X, 4 * M1);
  // QKV projections: 64x128 tile, 6 blocks/CU; bz=2 writes Vtg transposed
  gemm64_kernel<false, true><<<dim3(8, 64, 3), tb, 0, stream>>>(
      X, 4 * M1, Wtq, M1, Qb, nullptr, 4 * M1, Vtg, 4096, 1024, 1024);
  attn_kernel<<<dim3(16, 32), tba, 0, stream>>>(Qb, Qb + 4 * M1, Vtg, Cb);
  gemm64_kernel<true, false><<<dim3(8, 64, 1), tb, 0, stream>>>(
      Cb, 0, Wto, 0, nullptr, outp, 0, nullptr, 4096, 1024, 1024);
}

// Round 15
// 109.675 us; speedup vs baseline: 1.0453x; 1.0358x over previous
//
#include <hip/hip_runtime.h>

// MHA: out = softmax_causal((XWq)(XWk)^T / 8) (XWv) Wo
// B=2 S=2048 DM=1024 H=16 d=64. Inputs fp32, output fp32, bf16 MFMA compute.

typedef __attribute__((ext_vector_type(8))) short v8s;   // 8 x bf16 (4 VGPRs)
typedef __attribute__((ext_vector_type(4))) float v4f;   // MFMA accumulator

#define MFMA16(a, b, c) __builtin_amdgcn_mfma_f32_16x16x32_bf16(a, b, c, 0, 0, 0)

#define GLOBAL_AS __attribute__((address_space(1)))
#define LDS_AS __attribute__((address_space(3)))

__device__ __forceinline__ void gload_lds16(const void* g, void* l) {
  // async global->LDS, 16B per lane; LDS dest = wave-uniform base + lane*16
  __builtin_amdgcn_global_load_lds((const GLOBAL_AS void*)g, (LDS_AS void*)l, 16, 0, 0);
}

__device__ __forceinline__ short f2bf(float f) {
  union { float f; unsigned u; } x; x.f = f;
  unsigned r = x.u + 0x7fffu + ((x.u >> 16) & 1u);  // RNE
  return (short)(r >> 16);
}

// pack 2 f32 -> 1 dword of 2 bf16 (RNE), lo16 = bf16(a), hi16 = bf16(b)
__device__ __forceinline__ unsigned cvtpk_bf16(float a, float b) {
  unsigned r;
  asm("v_cvt_pk_bf16_f32 %0, %1, %2" : "=v"(r) : "v"(a), "v"(b));
  return r;
}

// hardware 2^x (underflows to 0 for masked -1e30 scores)
__device__ __forceinline__ float exp2_hw(float x) {
  float r;
  asm("v_exp_f32 %0, %1" : "=v"(r) : "v"(x));
  return r;
}

// ---------------------------------------------------------------------------
// Fused prep: weight transpose+cast (4 slices) + QKV input f32->bf16 cast
// (3 slabs), one launch. Blocks [0,1024): wtrans (z=bid>>8; z0 Wq with
// 0.125*log2e folded, z1 Wk, z2 Wv, z3 Wo -> Wt[n][k] bf16 at
// [Wto|Wtq|Wtk|Wtv]). Blocks [1024,7168): cast q/k/v -> X (bf16).
// ---------------------------------------------------------------------------
__global__ __launch_bounds__(256) void prep_kernel(const float* __restrict__ w0,
                                                   const float* __restrict__ w1,
                                                   const float* __restrict__ w2,
                                                   const float* __restrict__ w3,
                                                   short* __restrict__ wtbase,
                                                   const float* __restrict__ s0,
                                                   const float* __restrict__ s1,
                                                   const float* __restrict__ s2,
                                                   short* __restrict__ X,
                                                   size_t xstride) {
  __shared__ __align__(16) short tile[64 * 72];
  const int NN = 1024;
  int bid = blockIdx.x;
  int t = threadIdx.x;
  if (bid < 1024) {
    int z = bid >> 8;
    int rem = bid & 255;
    int n0 = (rem & 15) * 64, k0 = (rem >> 4) * 64;
    const float* W = (z == 0) ? w0 : (z == 1) ? w1 : (z == 2) ? w2 : w3;
    short* Wt = wtbase + ((z < 3) ? ((size_t)(z + 1) << 20) : 0);
    float scale = (z == 0) ? 0.125f * 1.44269504f : 1.0f;
    int r = t >> 4;
    int c4 = (t & 15) * 4;
    for (int rr = r; rr < 64; rr += 16) {
      float4 f = *(const float4*)(W + (size_t)(k0 + rr) * NN + n0 + c4);
      tile[(c4 + 0) * 72 + rr] = f2bf(f.x * scale);
      tile[(c4 + 1) * 72 + rr] = f2bf(f.y * scale);
      tile[(c4 + 2) * 72 + rr] = f2bf(f.z * scale);
      tile[(c4 + 3) * 72 + rr] = f2bf(f.w * scale);
    }
    __syncthreads();
    int nr = t >> 2, kc = (t & 3) * 16;
    v8s v0 = *(const v8s*)&tile[nr * 72 + kc];
    v8s v1 = *(const v8s*)&tile[nr * 72 + kc + 8];
    *(v8s*)(Wt + (size_t)(n0 + nr) * NN + k0 + kc) = v0;
    *(v8s*)(Wt + (size_t)(n0 + nr) * NN + k0 + kc + 8) = v1;
  } else {
    int c = bid - 1024;
    int z = c >> 11;
    const float* src = (z == 0) ? s0 : (z == 1) ? s1 : s2;
    short* d = X + (size_t)z * xstride;
    int i = ((c & 2047) * 256 + t) * 8;
    float4 f0 = *(const float4*)(src + i);
    float4 f1 = *(const float4*)(src + i + 4);
    v8s v;
    v[0] = f2bf(f0.x); v[1] = f2bf(f0.y); v[2] = f2bf(f0.z); v[3] = f2bf(f0.w);
    v[4] = f2bf(f1.x); v[5] = f2bf(f1.y); v[6] = f2bf(f1.z); v[7] = f2bf(f1.w);
    *(v8s*)(d + i) = v;
  }
}

// ---------------------------------------------------------------------------
// GEMM (R8/R12-proven): C = A[M][K] * Bt[N][K]^T, all-bf16, 128x128 tile,
// BK=32, 2-phase double-buffered, 32 KB LDS (5 blocks/CU), XOR-swizzled LDS
// via pre-swizzled DMA source (rule 21), XCD-aware remap (T1, nwg % 8 == 0).
// V_TRANS: bz==2 writes C transposed to Vt[bh][d][s] (fuses vtrans kernel).
// This 2-phase 128^2 structure measures 600 TF at K=1024 == the known
// structural ceiling for this geometry (m233/m248); 8-phase 256^2 doesn't
// fit (grid 192 < 256 CUs) and 64x128 regressed (R14, intensity halved).
// ---------------------------------------------------------------------------
template <bool OUT_F32, bool V_TRANS>
__global__ __launch_bounds__(256) void gemm2_kernel(
    const short* __restrict__ Ab, size_t sA,
    const short* __restrict__ Btb, size_t sB,
    short* __restrict__ Cb, float* __restrict__ Cf, size_t sC,
    short* __restrict__ Vt,
    int M, int N, int K) {
  __shared__ __align__(16) short As[2][128 * 32];  // 16 KB
  __shared__ __align__(16) short Bs[2][128 * 32];  // 16 KB

  // XCD-contiguous remap (bijective since nwg % 8 == 0)
  int gx = gridDim.x, gy = gridDim.y;
  int id = blockIdx.x + gx * (blockIdx.y + gy * blockIdx.z);
  int nwg = gx * gy * gridDim.z;
  int v = (id & 7) * (nwg >> 3) + (id >> 3);
  int bx = v % gx;
  int by = (v / gx) % gy;
  int bz = v / (gx * gy);

  const short* A = Ab + (size_t)bz * sA;
  const short* Bt = Btb + (size_t)bz * sB;
  int row0 = by * 128, col0 = bx * 128;
  int t = threadIdx.x, lane = t & 63, w = t >> 6;
  int wm = (w >> 1) * 64, wn = (w & 1) * 64;
  int lr = lane & 15, lg = lane >> 4;

  v4f acc[4][4];
#pragma unroll
  for (int i = 0; i < 4; ++i)
#pragma unroll
    for (int j = 0; j < 4; ++j) acc[i][j] = {0.f, 0.f, 0.f, 0.f};

  // DMA staging: 1KB chunks of 16 rows x 32k; wave w stages chunks {w, w+4}.
  // lane l -> phys row l>>2, slot l&3; source col slot = (l&3) ^ s(row),
  // s(row) = (row ^ (row>>2)) & 3 == read-side rsw.
  int rl = lane >> 2, sl = lane & 3;
  int scol = ((sl ^ (rl ^ (rl >> 2))) & 3) * 8;
  const short* gA = A + (size_t)(row0 + w * 16 + rl) * K + scol;
  const short* gB = Bt + (size_t)(col0 + w * 16 + rl) * K + scol;
  const size_t rstep = (size_t)64 * K;

#define GEMM_STAGE(buf, k0_)                              \
  do {                                                    \
    gload_lds16(gA + (k0_), &As[buf][w * 512]);           \
    gload_lds16(gA + rstep + (k0_), &As[buf][(w + 4) * 512]); \
    gload_lds16(gB + (k0_), &Bs[buf][w * 512]);           \
    gload_lds16(gB + rstep + (k0_), &Bs[buf][(w + 4) * 512]); \
  } while (0)

  GEMM_STAGE(0, 0);
  __syncthreads();
  int cur = 0;
  int rsw = (lr ^ (lr >> 2)) & 3;
  for (int k0 = 0; k0 < K; k0 += 32) {
    if (k0 + 32 < K) GEMM_STAGE(cur ^ 1, k0 + 32);
    v8s af[4], bg[4];
#pragma unroll
    for (int mf = 0; mf < 4; ++mf)
      af[mf] = *(const v8s*)&As[cur][(wm + mf * 16 + lr) * 32 + ((lg ^ rsw) * 8)];
#pragma unroll
    for (int nf = 0; nf < 4; ++nf)
      bg[nf] = *(const v8s*)&Bs[cur][(wn + nf * 16 + lr) * 32 + ((lg ^ rsw) * 8)];
    __builtin_amdgcn_s_setprio(1);
#pragma unroll
    for (int mf = 0; mf < 4; ++mf)
#pragma unroll
      for (int nf = 0; nf < 4; ++nf)
        acc[mf][nf] = MFMA16(af[mf], bg[nf], acc[mf][nf]);
    __builtin_amdgcn_s_setprio(0);
    __syncthreads();  // drains prefetch vmcnt + all LDS reads; 1 barrier/iter
    cur ^= 1;
  }
#undef GEMM_STAGE

  if (V_TRANS && bz == 2) {
    // write V transposed: Vt[bh][d][s], bh=b*16+h, h=col>>6, d=col&63;
    // the 4 acc rows are consecutive s -> one uint2 (4 bf16) store.
#pragma unroll
    for (int mf = 0; mf < 4; ++mf)
#pragma unroll
      for (int nf = 0; nf < 4; ++nf) {
        int col = col0 + wn + nf * 16 + lr;
        int row = row0 + wm + mf * 16 + lg * 4;
        int bh = ((row >> 11) << 4) + (col >> 6);
        int d = col & 63, s = row & 2047;
        uint2 u;
        u.x = cvtpk_bf16(acc[mf][nf][0], acc[mf][nf][1]);
        u.y = cvtpk_bf16(acc[mf][nf][2], acc[mf][nf][3]);
        *(uint2*)&Vt[((size_t)bh * 64 + d) * 2048 + s] = u;
      }
  } else {
#pragma unroll
    for (int mf = 0; mf < 4; ++mf)
#pragma unroll
      for (int nf = 0; nf < 4; ++nf)
#pragma unroll
        for (int r = 0; r < 4; ++r) {
          int row = row0 + wm + mf * 16 + lg * 4 + r;
          int col = col0 + wn + nf * 16 + lr;
          if (OUT_F32)
            (Cf + (size_t)bz * sC)[(size_t)row * N + col] = acc[mf][nf][r];
          else
            (Cb + (size_t)bz * sC)[(size_t)row * N + col] = f2bf(acc[mf][nf][r]);
        }
  }
}

// ---------------------------------------------------------------------------
// Causal flash attention (R12-proven), 512 threads / 8 waves per block.
// Wave w: q-row group g=w&3 (16 rows), key-half hh=w>>2 (32 of 64 keys/tile).
// Max-free exp2 softmax is associative -> key-partitioned partial O/den per
// wave, one cross-wave reduction at the end (LDS scratch reuses K/V bufs).
// Grid (16,32)=512 blocks; v=(id&7)*64+(id>>3) -> XCD x owns bh [4x,4x+4)
// (K/V L2-resident); px=v&15 -> q-tiles {31-px, px} sequential (33 iters).
// ---------------------------------------------------------------------------
__global__ __launch_bounds__(512, 4) void attn_kernel(const short* __restrict__ Qm,
                                                      const short* __restrict__ Km,
                                                      const short* __restrict__ Vt_g,
                                                      short* __restrict__ Cm) {
  const int S = 2048, DM = 1024;
  // Ks[2][4096] | Vs[2][4096] | Pt[8][640]  (43 KB); scr reuses Ks/Vs (20 KB)
  __shared__ __align__(16) short lds[21504];
  short* Ks0 = lds;
  short* Vs0 = lds + 8192;
  short* Pt = lds + 16384;
  v4f* scr = (v4f*)lds;

  int id = blockIdx.y * 16 + blockIdx.x;
  int v = (id & 7) * 64 + (id >> 3);    // XCD-contiguous remap (bijective)
  int bh = v >> 4;
  int px = v & 15;                      // q-tile pair {31-px, px}
  int b = bh >> 4, h = bh & 15;
  int t = threadIdx.x, lane = t & 63, w = t >> 6;  // w 0..7
  int g = w & 3, hh = w >> 2;
  int lr = lane & 15, lg = lane >> 4;
  size_t base = (size_t)b * S * DM + h * 64;
  size_t vbase = (size_t)bh * 64 * S;

  // staging: 16 chunks of 1KB (8 rows x 128B); wave w stages K-chunk w + V-chunk w
  int srow = w * 8 + (lane >> 3);
  int scol = ((lane & 7) ^ (lane >> 3)) * 8;
  const short* gK = Km + base + (size_t)srow * DM + scol;
  const short* gV = Vt_g + vbase + (size_t)srow * S + scol;
  int sw = (lr & 7) * 8;  // read swizzle (row & 7 == lr & 7 everywhere we read)

  const v8s vone = {0x3F80, 0x3F80, 0x3F80, 0x3F80,
                    0x3F80, 0x3F80, 0x3F80, 0x3F80};  // bf16 1.0 x8

#define ATTN_STAGE(buf, kt_)                                                  \
  do {                                                                        \
    size_t k0_ = (size_t)(kt_) * 64;                                          \
    gload_lds16(gK + k0_ * DM, &Ks0[(buf) * 4096 + w * 512]);                 \
    gload_lds16(gV + k0_, &Vs0[(buf) * 4096 + w * 512]);                      \
  } while (0)

  short* Cp = Cm + base;

#pragma unroll 1
  for (int qsel = 0; qsel < 2; ++qsel) {
    int qt = qsel ? px : (31 - px);  // long q-tile first
    int qbase = qt * 64 + g * 16;
    int qg = qbase + lr;
    int nkt = qt + 1;

    // Q fragments (B-operand rows, indexed by lr); 0.125*log2e folded into Wq
    const short* Qp = Qm + base + (size_t)(qbase + lr) * DM + lg * 8;
    v8s q0 = *(const v8s*)Qp;
    v8s q1 = *(const v8s*)(Qp + 32);

    v4f o[5];  // [0..3] = O cols d4*16+lr; [4] = sum(P) via ones-MFMA
#pragma unroll
    for (int d4 = 0; d4 < 5; ++d4) o[d4] = {0.f, 0.f, 0.f, 0.f};

    ATTN_STAGE(0, 0);
    __syncthreads();
    int cur = 0;
#pragma unroll 1
    for (int kt = 0; kt < nkt; ++kt) {
      if (kt + 1 < nkt) ATTN_STAGE(cur ^ 1, kt + 1);
      int k0 = kt * 64;
      const short* Kc = &Ks0[cur * 4096];
      const short* Vc = &Vs0[cur * 4096];

      // operand loads: this wave's key-half hh
      v8s ka0[2], ka1[2], vf[4];
#pragma unroll
      for (int t2 = 0; t2 < 2; ++t2) {
        int kr = hh * 32 + t2 * 16 + lr;
        ka0[t2] = *(const v8s*)&Kc[kr * 64 + ((lg * 8) ^ sw)];
        ka1[t2] = *(const v8s*)&Kc[kr * 64 + ((32 + lg * 8) ^ sw)];
      }
#pragma unroll
      for (int d4 = 0; d4 < 4; ++d4)
        vf[d4] = *(const v8s*)&Vc[(d4 * 16 + lr) * 64 + ((hh * 32 + lg * 8) ^ sw)];

      // S^T: st[t2][r] = S[q=lr][k0 + hh*32 + t2*16 + lg*4 + r] (exp2 domain)
      v4f st[2];
      __builtin_amdgcn_s_setprio(1);
#pragma unroll
      for (int t2 = 0; t2 < 2; ++t2) {
        v4f s = {0.f, 0.f, 0.f, 0.f};
        s = MFMA16(ka0[t2], q0, s);
        s = MFMA16(ka1[t2], q1, s);
        st[t2] = s;
      }
      __builtin_amdgcn_s_setprio(0);

      if (kt == nkt - 1) {  // causal mask (only last tile can violate)
#pragma unroll
        for (int t2 = 0; t2 < 2; ++t2)
#pragma unroll
          for (int r = 0; r < 4; ++r)
            if (k0 + hh * 32 + t2 * 16 + lg * 4 + r > qg) st[t2][r] = -1e30f;
      }

      // P = exp2(st); pack bf16; store to wave-private LDS
#pragma unroll
      for (int t2 = 0; t2 < 2; ++t2) {
        uint2 u;
        u.x = cvtpk_bf16(exp2_hw(st[t2][0]), exp2_hw(st[t2][1]));
        u.y = cvtpk_bf16(exp2_hw(st[t2][2]), exp2_hw(st[t2][3]));
        *(uint2*)&Pt[w * 640 + lr * 40 + t2 * 16 + lg * 4] = u;
      }
      v8s pa = *(const v8s*)&Pt[w * 640 + lr * 40 + lg * 8];

      // PV over this key-half + ones-MFMA denominator
      __builtin_amdgcn_s_setprio(1);
#pragma unroll
      for (int d4 = 0; d4 < 4; ++d4) o[d4] = MFMA16(pa, vf[d4], o[d4]);
      o[4] = MFMA16(pa, vone, o[4]);
      __builtin_amdgcn_s_setprio(0);
      __syncthreads();  // drains prefetch vmcnt + LDS reads; 1 barrier/iter
      cur ^= 1;
    }

    // cross-wave reduce (hh=1 partials into hh=0) and store
    if (hh == 1) {
#pragma unroll
      for (int d4 = 0; d4 < 5; ++d4) scr[(g * 5 + d4) * 64 + lane] = o[d4];
    }
    __syncthreads();
    if (hh == 0) {
#pragma unroll
      for (int d4 = 0; d4 < 5; ++d4) {
        v4f p = scr[(g * 5 + d4) * 64 + lane];
#pragma unroll
        for (int r = 0; r < 4; ++r) o[d4][r] += p[r];
      }
      float sv[4];
#pragma unroll
      for (int r = 0; r < 4; ++r) sv[r] = 1.0f / o[4][r];
#pragma unroll
      for (int r = 0; r < 4; ++r)
#pragma unroll
        for (int d4 = 0; d4 < 4; ++d4)
          Cp[(size_t)(qbase + lg * 4 + r) * DM + d4 * 16 + lr] =
              f2bf(o[d4][r] * sv[r]);
    }
    __syncthreads();  // scr/K/V region free before next q-tile stages into it
  }
#undef ATTN_STAGE
}

// ---------------------------------------------------------------------------
extern "C" void kernel_launch(void* const* d_in, const int* in_sizes, int n_in,
                              void* d_out, int out_size, void* d_ws, size_t ws_size,
                              hipStream_t stream) {
  const float* q_in = (const float*)d_in[0];
  const float* k_in = (const float*)d_in[1];
  const float* v_in = (const float*)d_in[2];
  // d_in[3] = mask: causal triu(k=1), applied analytically in attn_kernel
  const float* w_q = (const float*)d_in[4];
  const float* w_k = (const float*)d_in[5];
  const float* w_v = (const float*)d_in[6];
  const float* w_o = (const float*)d_in[7];
  float* outp = (float*)d_out;

  short* ws = (short*)d_ws;
  const size_t M1 = (size_t)1 << 20;  // 1M shorts = 2MB
  // Layout (64MB of ws): Wt[0:4M)=[Wto|Wtq|Wtk|Wtv], X[4:16M) bf16
  // QKV inputs, Qb[16:20M), Kb[20:24M), Vtg[24:28M), Cb[28:32M).
  short* Wto = ws;
  short* Wtq = ws + 1 * M1;
  short* X = ws + 4 * M1;
  short* Qb = ws + 16 * M1;
  short* Vtg = ws + 24 * M1;
  short* Cb = ws + 28 * M1;
  dim3 tb(256);
  dim3 tba(512);

  // fused weight-transpose + input-cast (one launch)
  prep_kernel<<<dim3(7168), tb, 0, stream>>>(w_q, w_k, w_v, w_o, ws,
                                             q_in, k_in, v_in, X, 4 * M1);
  // QKV projections: 128x128 2-phase (proven); bz=2 writes Vtg transposed
  gemm2_kernel<false, true><<<dim3(8, 32, 3), tb, 0, stream>>>(
      X, 4 * M1, Wtq, M1, Qb, nullptr, 4 * M1, Vtg, 4096, 1024, 1024);
  attn_kernel<<<dim3(16, 32), tba, 0, stream>>>(Qb, Qb + 4 * M1, Vtg, Cb);
  gemm2_kernel<true, false><<<dim3(8, 32, 1), tb, 0, stream>>>(
      Cb, 0, Wto, 0, nullptr, outp, 0, nullptr, 4096, 1024, 1024);
}